// Round 5
// baseline (328.275 us; speedup 1.0000x reference)
//
#include <hip/hip_runtime.h>
#include <hip/hip_fp16.h>

#define THREADS 256

typedef union { uint2 u; __half2 h[2]; } H4;

// ---------------- CSR build ----------------

// counts[d]++ and record per-edge sequence number (order within row irrelevant: sum).
__global__ void k_count(const int* __restrict__ dst, int* __restrict__ counts,
                        int* __restrict__ seq, int E) {
    int t = blockIdx.x * blockDim.x + threadIdx.x;
    if (t < E) seq[t] = atomicAdd(&counts[dst[t]], 1);
}

// Block-local exclusive scan of counts + dinv/s1 computation + t init.
__global__ void k_scan1(const int* __restrict__ counts, const float* __restrict__ x,
                        float* __restrict__ dinv, float* __restrict__ s1,
                        float* __restrict__ t, int* __restrict__ rowloc,
                        int* __restrict__ blocksums) {
    __shared__ int s[256];
    int i = blockIdx.x * 256 + threadIdx.x;
    int c = counts[i];
    float d = rsqrtf((float)c + 1.0f);
    dinv[i] = d;
    float sv = x[i] * d;
    s1[i] = sv;
    t[i] = sv;                       // self term of layer-1 aggregation
    s[threadIdx.x] = c;
    __syncthreads();
    for (int off = 1; off < 256; off <<= 1) {
        int v = (threadIdx.x >= off) ? s[threadIdx.x - off] : 0;
        __syncthreads();
        s[threadIdx.x] += v;
        __syncthreads();
    }
    rowloc[i] = s[threadIdx.x] - c;  // block-local exclusive prefix
    if (threadIdx.x == 255) blocksums[blockIdx.x] = s[255];
}

// Fused: esrc fill (atomic-free via seq) + layer-1 scalar aggregation atomics
// + finalized rowstart emission (blocks 0..255). Each block re-scans the 256
// block sums in LDS (cheap) instead of a separate scan kernel.
__global__ void k_fill(const int* __restrict__ src, const int* __restrict__ dst,
                       const int* __restrict__ rowloc, const int* __restrict__ seq,
                       const int* __restrict__ blocksums, const float* __restrict__ s1,
                       int* __restrict__ esrc, float* __restrict__ t,
                       int* __restrict__ rowstart, int E) {
    __shared__ int boff[256];
    {
        int c = blocksums[threadIdx.x];
        boff[threadIdx.x] = c;
        __syncthreads();
        for (int off = 1; off < 256; off <<= 1) {
            int v = (threadIdx.x >= off) ? boff[threadIdx.x - off] : 0;
            __syncthreads();
            boff[threadIdx.x] += v;
            __syncthreads();
        }
        boff[threadIdx.x] -= c;      // exclusive
        __syncthreads();
    }
    int e = blockIdx.x * blockDim.x + threadIdx.x;
    if (e < E) {
        int d = dst[e];
        int sg = src[e];
        int p = rowloc[d] + boff[d >> 8] + seq[e];
        esrc[p] = sg;
        atomicAdd(&t[d], s1[sg]);    // layer-1 aggregation fused here
    }
    if (blockIdx.x < 256) {          // finalize rowstart (separate array: no race)
        int i = blockIdx.x * 256 + threadIdx.x;
        rowstart[i] = rowloc[i] + boff[blockIdx.x];
    }
}

// ---------------- Fused layer1-activation + layer2 GEMM (fp16 output) ----------------
#define L12_R 8
__global__ void k_l1l2(const float* __restrict__ t, const float* __restrict__ dinv,
                       const float* __restrict__ W1, const float* __restrict__ b1,
                       const float* __restrict__ W2, __half* __restrict__ xws2, int N) {
    __shared__ float wb[128 * 2];
    __shared__ float W2s[128 * 64];
    for (int idx = threadIdx.x; idx < 128; idx += 256) {
        wb[idx * 2] = W1[idx];
        wb[idx * 2 + 1] = b1[idx];
    }
    for (int idx = threadIdx.x; idx < 128 * 64 / 4; idx += 256)
        reinterpret_cast<float4*>(W2s)[idx] = reinterpret_cast<const float4*>(W2)[idx];
    __syncthreads();

    int c4 = threadIdx.x & 15;
    int rg = threadIdx.x >> 4;
    int base = blockIdx.x * (16 * L12_R) + rg * L12_R;

    float a[L12_R];
#pragma unroll
    for (int r = 0; r < L12_R; ++r) {
        int i = base + r;
        a[r] = (i < N) ? dinv[i] * t[i] : 0.f;
    }
    float4 acc[L12_R] = {};
    for (int k = 0; k < 128; ++k) {
        float2 w1b1 = *reinterpret_cast<const float2*>(&wb[k * 2]);
        float4 w2 = *reinterpret_cast<const float4*>(&W2s[k * 64 + c4 * 4]);
#pragma unroll
        for (int r = 0; r < L12_R; ++r) {
            float h = fmaxf(fmaf(a[r], w1b1.x, w1b1.y), 0.f);
            acc[r].x = fmaf(h, w2.x, acc[r].x);
            acc[r].y = fmaf(h, w2.y, acc[r].y);
            acc[r].z = fmaf(h, w2.z, acc[r].z);
            acc[r].w = fmaf(h, w2.w, acc[r].w);
        }
    }
#pragma unroll
    for (int r = 0; r < L12_R; ++r) {
        int i = base + r;
        if (i < N) {
            float di = dinv[i];
            H4 o;
            o.h[0] = __floats2half2_rn(acc[r].x * di, acc[r].y * di);
            o.h[1] = __floats2half2_rn(acc[r].z * di, acc[r].w * di);
            reinterpret_cast<uint2*>(xws2)[(size_t)i * 16 + c4] = o.u;
        }
    }
}

// ---------------- Fused gather2 (+relu+bias) + layer3 GEMM (fp16 in/out) ----------------
__global__ void k_l2l3(const int* __restrict__ rowstart, const int* __restrict__ counts,
                       const int* __restrict__ esrc, const __half* __restrict__ xws2,
                       const float* __restrict__ dinv, const float* __restrict__ b2,
                       const float* __restrict__ W3, __half* __restrict__ xws3, int N) {
    __shared__ float W3s[64 * 32];
    __shared__ float h2s[16][64];
    __shared__ float b2s[64];
    for (int idx = threadIdx.x; idx < 64 * 32 / 4; idx += 256)
        reinterpret_cast<float4*>(W3s)[idx] = reinterpret_cast<const float4*>(W3)[idx];
    if (threadIdx.x < 64) b2s[threadIdx.x] = b2[threadIdx.x];
    __syncthreads();

    {
        int c4 = threadIdx.x & 15;
        int r  = threadIdx.x >> 4;
        int i  = blockIdx.x * 16 + r;
        if (i < N) {
            const uint2* x2 = reinterpret_cast<const uint2*>(xws2);
            H4 p; p.u = x2[(size_t)i * 16 + c4];
            float2 f0 = __half22float2(p.h[0]), f1 = __half22float2(p.h[1]);
            float4 acc = {f0.x, f0.y, f1.x, f1.y};
            int s0 = rowstart[i], cnt = counts[i];
            for (int q = s0; q < s0 + cnt; ++q) {
                int s = esrc[q];
                p.u = x2[(size_t)s * 16 + c4];
                f0 = __half22float2(p.h[0]); f1 = __half22float2(p.h[1]);
                acc.x += f0.x; acc.y += f0.y; acc.z += f1.x; acc.w += f1.y;
            }
            float di = dinv[i];
            float4 bv = *reinterpret_cast<const float4*>(&b2s[c4 * 4]);
            float4 h;
            h.x = fmaxf(fmaf(di, acc.x, bv.x), 0.f);
            h.y = fmaxf(fmaf(di, acc.y, bv.y), 0.f);
            h.z = fmaxf(fmaf(di, acc.z, bv.z), 0.f);
            h.w = fmaxf(fmaf(di, acc.w, bv.w), 0.f);
            *reinterpret_cast<float4*>(&h2s[r][c4 * 4]) = h;
        }
    }
    __syncthreads();
    {
        int c  = threadIdx.x & 15;
        int r2 = threadIdx.x >> 4;
        int i2 = blockIdx.x * 16 + r2;
        if (i2 >= N) return;
        float acc0 = 0.f, acc1 = 0.f;
#pragma unroll
        for (int k = 0; k < 64; ++k) {
            float h = h2s[r2][k];
            float2 w = *reinterpret_cast<const float2*>(&W3s[k * 32 + 2 * c]);
            acc0 = fmaf(h, w.x, acc0);
            acc1 = fmaf(h, w.y, acc1);
        }
        float di = dinv[i2];
        reinterpret_cast<__half2*>(xws3)[(size_t)i2 * 16 + c] =
            __floats2half2_rn(acc0 * di, acc1 * di);
    }
}

// ---------------- Fused gather3 + mean-pool partials + last-block FC ----------------
__global__ void k_l3pool(const int* __restrict__ rowstart, const int* __restrict__ counts,
                         const int* __restrict__ esrc, const __half* __restrict__ xws3,
                         const float* __restrict__ dinv, const float* __restrict__ b3,
                         const int* __restrict__ batch, float* __restrict__ sums,
                         float* __restrict__ cnt, int* __restrict__ ticket,
                         const float* __restrict__ Wfc, const float* __restrict__ bfc,
                         float* __restrict__ out, int N, int nblocks) {
    __shared__ float sl[64 * 32];
    __shared__ float cl[64];
    __shared__ int lastflag;
    for (int idx = threadIdx.x; idx < 64 * 32; idx += 256) sl[idx] = 0.f;
    if (threadIdx.x < 64) cl[threadIdx.x] = 0.f;
    __syncthreads();

    int c4 = threadIdx.x & 7;
    int r  = threadIdx.x >> 3;
    int i  = blockIdx.x * 32 + r;
    if (i < N) {
        const uint2* x2 = reinterpret_cast<const uint2*>(xws3);
        H4 p; p.u = x2[(size_t)i * 8 + c4];
        float2 f0 = __half22float2(p.h[0]), f1 = __half22float2(p.h[1]);
        float4 acc = {f0.x, f0.y, f1.x, f1.y};
        int s0 = rowstart[i], cc = counts[i];
        for (int q = s0; q < s0 + cc; ++q) {
            int s = esrc[q];
            p.u = x2[(size_t)s * 8 + c4];
            f0 = __half22float2(p.h[0]); f1 = __half22float2(p.h[1]);
            acc.x += f0.x; acc.y += f0.y; acc.z += f1.x; acc.w += f1.y;
        }
        float di = dinv[i];
        const float4 bv = reinterpret_cast<const float4*>(b3)[c4];
        int g = batch[i];
        atomicAdd(&sl[g * 32 + c4 * 4 + 0], fmaxf(fmaf(di, acc.x, bv.x), 0.f));
        atomicAdd(&sl[g * 32 + c4 * 4 + 1], fmaxf(fmaf(di, acc.y, bv.y), 0.f));
        atomicAdd(&sl[g * 32 + c4 * 4 + 2], fmaxf(fmaf(di, acc.z, bv.z), 0.f));
        atomicAdd(&sl[g * 32 + c4 * 4 + 3], fmaxf(fmaf(di, acc.w, bv.w), 0.f));
        if (c4 == 0) atomicAdd(&cl[g], 1.f);
    }
    __syncthreads();

    // Flush this block's narrow graph range to global.
    int start = blockIdx.x * 32;
    if (start < N) {
        int g0 = batch[start];
        int g1 = batch[min(start + 31, N - 1)];
        int ng = g1 - g0 + 1;
        for (int idx = threadIdx.x; idx < ng * 32; idx += 256) {
            float v = sl[(g0 + idx / 32) * 32 + (idx & 31)];
            if (v != 0.f) atomicAdd(&sums[(g0 + idx / 32) * 32 + (idx & 31)], v);
        }
        for (int idx = threadIdx.x; idx < ng; idx += 256) {
            float v = cl[g0 + idx];
            if (v != 0.f) atomicAdd(&cnt[g0 + idx], v);
        }
    }

    // Last block computes the FC head.
    __threadfence();
    __syncthreads();
    if (threadIdx.x == 0) lastflag = (atomicAdd(ticket, 1) == nblocks - 1) ? 1 : 0;
    __syncthreads();
    if (!lastflag) return;

    for (int idx = threadIdx.x; idx < 64 * 32; idx += 256)
        sl[idx] = __hip_atomic_load(&sums[idx], __ATOMIC_RELAXED, __HIP_MEMORY_SCOPE_AGENT);
    for (int idx = threadIdx.x; idx < 64; idx += 256)
        cl[idx] = __hip_atomic_load(&cnt[idx], __ATOMIC_RELAXED, __HIP_MEMORY_SCOPE_AGENT);
    __syncthreads();
    for (int tix = threadIdx.x; tix < 640; tix += 256) {
        int g = tix / 10, o = tix % 10;
        float inv = 1.0f / fmaxf(cl[g], 1.0f);
        float acc = bfc[o];
#pragma unroll
        for (int f = 0; f < 32; ++f) acc = fmaf(sl[g * 32 + f] * inv, Wfc[f * 10 + o], acc);
        out[tix] = acc;
    }
}

extern "C" void kernel_launch(void* const* d_in, const int* in_sizes, int n_in,
                              void* d_out, int out_size, void* d_ws, size_t ws_size,
                              hipStream_t stream) {
    const float* x    = (const float*)d_in[0];
    const int*   ei   = (const int*)d_in[1];
    const int*   batch= (const int*)d_in[2];
    const float* W1   = (const float*)d_in[3];
    const float* b1   = (const float*)d_in[4];
    const float* W2   = (const float*)d_in[5];
    const float* b2   = (const float*)d_in[6];
    const float* W3   = (const float*)d_in[7];
    const float* b3   = (const float*)d_in[8];
    const float* Wfc  = (const float*)d_in[9];
    const float* bfc  = (const float*)d_in[10];
    float* out = (float*)d_out;

    const int N = in_sizes[0];
    const int E = in_sizes[1] / 2;
    const int* src  = ei;
    const int* dstp = ei + E;

    char* ws = (char*)d_ws;
    size_t off = 0;
    auto alloc = [&](size_t bytes) { void* p = ws + off; off = (off + bytes + 15) & ~(size_t)15; return p; };
    // --- contiguous zero region: counts | sums | cnt | ticket ---
    int*    counts   = (int*)   alloc((size_t)N * 4);
    float*  sums     = (float*) alloc(64 * 32 * 4);
    float*  cnt      = (float*) alloc(64 * 4);
    int*    ticket   = (int*)   alloc(16);
    size_t  zbytes   = (size_t)((char*)ticket + 16 - (char*)counts);
    // --- rest ---
    int*    rowloc   = (int*)   alloc((size_t)N * 4);
    int*    rowstart = (int*)   alloc((size_t)N * 4);
    int*    seq      = (int*)   alloc((size_t)E * 4);
    int*    blocksums= (int*)   alloc(256 * 4);
    int*    esrc     = (int*)   alloc((size_t)E * 4);
    float*  dinv     = (float*) alloc((size_t)N * 4);
    float*  s1       = (float*) alloc((size_t)N * 4);
    float*  tsum     = (float*) alloc((size_t)N * 4);
    __half* xws2     = (__half*)alloc((size_t)N * 64 * 2);
    __half* xws3     = (__half*)alloc((size_t)N * 32 * 2);

    auto blocks = [](long n) { return (int)((n + THREADS - 1) / THREADS); };

    hipMemsetAsync(counts, 0, zbytes, stream);

    k_count<<<blocks(E), THREADS, 0, stream>>>(dstp, counts, seq, E);
    k_scan1<<<N / 256, 256, 0, stream>>>(counts, x, dinv, s1, tsum, rowloc, blocksums);
    k_fill <<<blocks(E), THREADS, 0, stream>>>(src, dstp, rowloc, seq, blocksums, s1,
                                               esrc, tsum, rowstart, E);
    k_l1l2<<<(N + 16 * L12_R - 1) / (16 * L12_R), THREADS, 0, stream>>>(tsum, dinv, W1, b1, W2, xws2, N);
    k_l2l3<<<(N + 15) / 16, THREADS, 0, stream>>>(rowstart, counts, esrc, xws2, dinv, b2, W3, xws3, N);
    int npool = (N + 31) / 32;
    k_l3pool<<<npool, THREADS, 0, stream>>>(rowstart, counts, esrc, xws3, dinv, b3, batch,
                                            sums, cnt, ticket, Wfc, bfc, out, N, npool);
}

// Round 6
// 222.211 us; speedup vs baseline: 1.4773x; 1.4773x over previous
//
#include <hip/hip_runtime.h>
#include <hip/hip_fp16.h>

#define THREADS 256

typedef union { uint2 u; __half2 h[2]; } H4;

// ---------------- CSR build ----------------

// counts[d]++ and record per-edge sequence number (order within row irrelevant: sum).
__global__ void k_count(const int* __restrict__ dst, int* __restrict__ counts,
                        int* __restrict__ seq, int E) {
    int t = blockIdx.x * blockDim.x + threadIdx.x;
    if (t < E) seq[t] = atomicAdd(&counts[dst[t]], 1);
}

// Block-local exclusive scan of counts + dinv/s1 computation + t init.
__global__ void k_scan1(const int* __restrict__ counts, const float* __restrict__ x,
                        float* __restrict__ dinv, float* __restrict__ s1,
                        float* __restrict__ t, int* __restrict__ rowloc,
                        int* __restrict__ blocksums) {
    __shared__ int s[256];
    int i = blockIdx.x * 256 + threadIdx.x;
    int c = counts[i];
    float d = rsqrtf((float)c + 1.0f);
    dinv[i] = d;
    float sv = x[i] * d;
    s1[i] = sv;
    t[i] = sv;                       // self term of layer-1 aggregation
    s[threadIdx.x] = c;
    __syncthreads();
    for (int off = 1; off < 256; off <<= 1) {
        int v = (threadIdx.x >= off) ? s[threadIdx.x - off] : 0;
        __syncthreads();
        s[threadIdx.x] += v;
        __syncthreads();
    }
    rowloc[i] = s[threadIdx.x] - c;  // block-local exclusive prefix
    if (threadIdx.x == 255) blocksums[blockIdx.x] = s[255];
}

// Fused: esrc fill (atomic-free via seq) + layer-1 scalar aggregation atomics
// + finalized rowstart emission (blocks 0..255). Each block re-scans the 256
// block sums in LDS (cheap) instead of a separate scan kernel.
__global__ void k_fill(const int* __restrict__ src, const int* __restrict__ dst,
                       const int* __restrict__ rowloc, const int* __restrict__ seq,
                       const int* __restrict__ blocksums, const float* __restrict__ s1,
                       int* __restrict__ esrc, float* __restrict__ t,
                       int* __restrict__ rowstart, int E) {
    __shared__ int boff[256];
    {
        int c = blocksums[threadIdx.x];
        boff[threadIdx.x] = c;
        __syncthreads();
        for (int off = 1; off < 256; off <<= 1) {
            int v = (threadIdx.x >= off) ? boff[threadIdx.x - off] : 0;
            __syncthreads();
            boff[threadIdx.x] += v;
            __syncthreads();
        }
        boff[threadIdx.x] -= c;      // exclusive
        __syncthreads();
    }
    int e = blockIdx.x * blockDim.x + threadIdx.x;
    if (e < E) {
        int d = dst[e];
        int sg = src[e];
        int p = rowloc[d] + boff[d >> 8] + seq[e];
        esrc[p] = sg;
        atomicAdd(&t[d], s1[sg]);    // layer-1 aggregation fused here
    }
    if (blockIdx.x < 256) {          // finalize rowstart (separate array: no race)
        int i = blockIdx.x * 256 + threadIdx.x;
        rowstart[i] = rowloc[i] + boff[blockIdx.x];
    }
}

// ---------------- Fused layer1-activation + layer2 GEMM (fp16 output) ----------------
#define L12_R 8
__global__ void k_l1l2(const float* __restrict__ t, const float* __restrict__ dinv,
                       const float* __restrict__ W1, const float* __restrict__ b1,
                       const float* __restrict__ W2, __half* __restrict__ xws2, int N) {
    __shared__ float wb[128 * 2];
    __shared__ float W2s[128 * 64];
    for (int idx = threadIdx.x; idx < 128; idx += 256) {
        wb[idx * 2] = W1[idx];
        wb[idx * 2 + 1] = b1[idx];
    }
    for (int idx = threadIdx.x; idx < 128 * 64 / 4; idx += 256)
        reinterpret_cast<float4*>(W2s)[idx] = reinterpret_cast<const float4*>(W2)[idx];
    __syncthreads();

    int c4 = threadIdx.x & 15;
    int rg = threadIdx.x >> 4;
    int base = blockIdx.x * (16 * L12_R) + rg * L12_R;

    float a[L12_R];
#pragma unroll
    for (int r = 0; r < L12_R; ++r) {
        int i = base + r;
        a[r] = (i < N) ? dinv[i] * t[i] : 0.f;
    }
    float4 acc[L12_R] = {};
    for (int k = 0; k < 128; ++k) {
        float2 w1b1 = *reinterpret_cast<const float2*>(&wb[k * 2]);
        float4 w2 = *reinterpret_cast<const float4*>(&W2s[k * 64 + c4 * 4]);
#pragma unroll
        for (int r = 0; r < L12_R; ++r) {
            float h = fmaxf(fmaf(a[r], w1b1.x, w1b1.y), 0.f);
            acc[r].x = fmaf(h, w2.x, acc[r].x);
            acc[r].y = fmaf(h, w2.y, acc[r].y);
            acc[r].z = fmaf(h, w2.z, acc[r].z);
            acc[r].w = fmaf(h, w2.w, acc[r].w);
        }
    }
#pragma unroll
    for (int r = 0; r < L12_R; ++r) {
        int i = base + r;
        if (i < N) {
            float di = dinv[i];
            H4 o;
            o.h[0] = __floats2half2_rn(acc[r].x * di, acc[r].y * di);
            o.h[1] = __floats2half2_rn(acc[r].z * di, acc[r].w * di);
            reinterpret_cast<uint2*>(xws2)[(size_t)i * 16 + c4] = o.u;
        }
    }
}

// ---------------- Fused gather2 (+relu+bias) + layer3 GEMM (fp16 in/out) ----------------
__global__ void k_l2l3(const int* __restrict__ rowstart, const int* __restrict__ counts,
                       const int* __restrict__ esrc, const __half* __restrict__ xws2,
                       const float* __restrict__ dinv, const float* __restrict__ b2,
                       const float* __restrict__ W3, __half* __restrict__ xws3, int N) {
    __shared__ float W3s[64 * 32];
    __shared__ float h2s[16][64];
    __shared__ float b2s[64];
    for (int idx = threadIdx.x; idx < 64 * 32 / 4; idx += 256)
        reinterpret_cast<float4*>(W3s)[idx] = reinterpret_cast<const float4*>(W3)[idx];
    if (threadIdx.x < 64) b2s[threadIdx.x] = b2[threadIdx.x];
    __syncthreads();

    {
        int c4 = threadIdx.x & 15;
        int r  = threadIdx.x >> 4;
        int i  = blockIdx.x * 16 + r;
        if (i < N) {
            const uint2* x2 = reinterpret_cast<const uint2*>(xws2);
            H4 p; p.u = x2[(size_t)i * 16 + c4];
            float2 f0 = __half22float2(p.h[0]), f1 = __half22float2(p.h[1]);
            float4 acc = {f0.x, f0.y, f1.x, f1.y};
            int s0 = rowstart[i], cnt = counts[i];
            for (int q = s0; q < s0 + cnt; ++q) {
                int s = esrc[q];
                p.u = x2[(size_t)s * 16 + c4];
                f0 = __half22float2(p.h[0]); f1 = __half22float2(p.h[1]);
                acc.x += f0.x; acc.y += f0.y; acc.z += f1.x; acc.w += f1.y;
            }
            float di = dinv[i];
            float4 bv = *reinterpret_cast<const float4*>(&b2s[c4 * 4]);
            float4 h;
            h.x = fmaxf(fmaf(di, acc.x, bv.x), 0.f);
            h.y = fmaxf(fmaf(di, acc.y, bv.y), 0.f);
            h.z = fmaxf(fmaf(di, acc.z, bv.z), 0.f);
            h.w = fmaxf(fmaf(di, acc.w, bv.w), 0.f);
            *reinterpret_cast<float4*>(&h2s[r][c4 * 4]) = h;
        }
    }
    __syncthreads();
    {
        int c  = threadIdx.x & 15;
        int r2 = threadIdx.x >> 4;
        int i2 = blockIdx.x * 16 + r2;
        if (i2 >= N) return;
        float acc0 = 0.f, acc1 = 0.f;
#pragma unroll
        for (int k = 0; k < 64; ++k) {
            float h = h2s[r2][k];
            float2 w = *reinterpret_cast<const float2*>(&W3s[k * 32 + 2 * c]);
            acc0 = fmaf(h, w.x, acc0);
            acc1 = fmaf(h, w.y, acc1);
        }
        float di = dinv[i2];
        reinterpret_cast<__half2*>(xws3)[(size_t)i2 * 16 + c] =
            __floats2half2_rn(acc0 * di, acc1 * di);
    }
}

// ---------------- Fused gather3 (+relu+bias) + mean-pool partials (fp16 in) ----------------
// NO device-scope fence here: the round-5 last-block-FC experiment showed
// per-block __threadfence() costs ~120 us on gfx950 (L2 writeback per block).
__global__ void k_l3pool(const int* __restrict__ rowstart, const int* __restrict__ counts,
                         const int* __restrict__ esrc, const __half* __restrict__ xws3,
                         const float* __restrict__ dinv, const float* __restrict__ b3,
                         const int* __restrict__ batch, float* __restrict__ sums,
                         float* __restrict__ cnt, int N) {
    __shared__ float sl[64 * 32];
    __shared__ float cl[64];
    for (int idx = threadIdx.x; idx < 64 * 32; idx += 256) sl[idx] = 0.f;
    if (threadIdx.x < 64) cl[threadIdx.x] = 0.f;
    __syncthreads();

    int c4 = threadIdx.x & 7;
    int r  = threadIdx.x >> 3;
    int i  = blockIdx.x * 32 + r;
    if (i < N) {
        const uint2* x2 = reinterpret_cast<const uint2*>(xws3);
        H4 p; p.u = x2[(size_t)i * 8 + c4];
        float2 f0 = __half22float2(p.h[0]), f1 = __half22float2(p.h[1]);
        float4 acc = {f0.x, f0.y, f1.x, f1.y};
        int s0 = rowstart[i], cc = counts[i];
        for (int q = s0; q < s0 + cc; ++q) {
            int s = esrc[q];
            p.u = x2[(size_t)s * 8 + c4];
            f0 = __half22float2(p.h[0]); f1 = __half22float2(p.h[1]);
            acc.x += f0.x; acc.y += f0.y; acc.z += f1.x; acc.w += f1.y;
        }
        float di = dinv[i];
        const float4 bv = reinterpret_cast<const float4*>(b3)[c4];
        int g = batch[i];
        atomicAdd(&sl[g * 32 + c4 * 4 + 0], fmaxf(fmaf(di, acc.x, bv.x), 0.f));
        atomicAdd(&sl[g * 32 + c4 * 4 + 1], fmaxf(fmaf(di, acc.y, bv.y), 0.f));
        atomicAdd(&sl[g * 32 + c4 * 4 + 2], fmaxf(fmaf(di, acc.z, bv.z), 0.f));
        atomicAdd(&sl[g * 32 + c4 * 4 + 3], fmaxf(fmaf(di, acc.w, bv.w), 0.f));
        if (c4 == 0) atomicAdd(&cl[g], 1.f);
    }
    __syncthreads();

    int start = blockIdx.x * 32;
    if (start >= N) return;
    int g0 = batch[start];
    int g1 = batch[min(start + 31, N - 1)];
    int ng = g1 - g0 + 1;
    for (int idx = threadIdx.x; idx < ng * 32; idx += 256) {
        float v = sl[(g0 + idx / 32) * 32 + (idx & 31)];
        if (v != 0.f) atomicAdd(&sums[(g0 + idx / 32) * 32 + (idx & 31)], v);
    }
    for (int idx = threadIdx.x; idx < ng; idx += 256) {
        float v = cl[g0 + idx];
        if (v != 0.f) atomicAdd(&cnt[g0 + idx], v);
    }
}

__global__ void k_fc(const float* __restrict__ sums, const float* __restrict__ cnt,
                     const float* __restrict__ Wfc, const float* __restrict__ bfc,
                     float* __restrict__ out) {
    int t = blockIdx.x * blockDim.x + threadIdx.x;
    if (t >= 64 * 10) return;
    int g = t / 10, o = t % 10;
    float inv = 1.0f / fmaxf(cnt[g], 1.0f);
    float acc = bfc[o];
#pragma unroll
    for (int f = 0; f < 32; ++f) acc = fmaf(sums[g * 32 + f] * inv, Wfc[f * 10 + o], acc);
    out[t] = acc;
}

extern "C" void kernel_launch(void* const* d_in, const int* in_sizes, int n_in,
                              void* d_out, int out_size, void* d_ws, size_t ws_size,
                              hipStream_t stream) {
    const float* x    = (const float*)d_in[0];
    const int*   ei   = (const int*)d_in[1];
    const int*   batch= (const int*)d_in[2];
    const float* W1   = (const float*)d_in[3];
    const float* b1   = (const float*)d_in[4];
    const float* W2   = (const float*)d_in[5];
    const float* b2   = (const float*)d_in[6];
    const float* W3   = (const float*)d_in[7];
    const float* b3   = (const float*)d_in[8];
    const float* Wfc  = (const float*)d_in[9];
    const float* bfc  = (const float*)d_in[10];
    float* out = (float*)d_out;

    const int N = in_sizes[0];
    const int E = in_sizes[1] / 2;
    const int* src  = ei;
    const int* dstp = ei + E;

    char* ws = (char*)d_ws;
    size_t off = 0;
    auto alloc = [&](size_t bytes) { void* p = ws + off; off = (off + bytes + 15) & ~(size_t)15; return p; };
    // --- contiguous zero region: counts | sums | cnt ---
    int*    counts   = (int*)   alloc((size_t)N * 4);
    float*  sums     = (float*) alloc(64 * 32 * 4);
    float*  cnt      = (float*) alloc(64 * 4);
    size_t  zbytes   = (size_t)((char*)(cnt + 64) - (char*)counts);
    // --- rest ---
    int*    rowloc   = (int*)   alloc((size_t)N * 4);
    int*    rowstart = (int*)   alloc((size_t)N * 4);
    int*    seq      = (int*)   alloc((size_t)E * 4);
    int*    blocksums= (int*)   alloc(256 * 4);
    int*    esrc     = (int*)   alloc((size_t)E * 4);
    float*  dinv     = (float*) alloc((size_t)N * 4);
    float*  s1       = (float*) alloc((size_t)N * 4);
    float*  tsum     = (float*) alloc((size_t)N * 4);
    __half* xws2     = (__half*)alloc((size_t)N * 64 * 2);
    __half* xws3     = (__half*)alloc((size_t)N * 32 * 2);

    auto blocks = [](long n) { return (int)((n + THREADS - 1) / THREADS); };

    hipMemsetAsync(counts, 0, zbytes, stream);

    k_count<<<blocks(E), THREADS, 0, stream>>>(dstp, counts, seq, E);
    k_scan1<<<N / 256, 256, 0, stream>>>(counts, x, dinv, s1, tsum, rowloc, blocksums);
    k_fill <<<blocks(E), THREADS, 0, stream>>>(src, dstp, rowloc, seq, blocksums, s1,
                                               esrc, tsum, rowstart, E);
    k_l1l2<<<(N + 16 * L12_R - 1) / (16 * L12_R), THREADS, 0, stream>>>(tsum, dinv, W1, b1, W2, xws2, N);
    k_l2l3<<<(N + 15) / 16, THREADS, 0, stream>>>(rowstart, counts, esrc, xws2, dinv, b2, W3, xws3, N);
    k_l3pool<<<(N + 31) / 32, THREADS, 0, stream>>>(rowstart, counts, esrc, xws3, dinv, b3, batch,
                                                    sums, cnt, N);
    k_fc<<<blocks(640), THREADS, 0, stream>>>(sums, cnt, Wfc, bfc, out);
}

// Round 7
// 200.330 us; speedup vs baseline: 1.6387x; 1.1092x over previous
//
#include <hip/hip_runtime.h>
#include <hip/hip_fp16.h>

#define THREADS 256

typedef union { uint2 u; __half2 h[2]; } H4;

// ---------------- CSR build ----------------

// counts[d]++ and record per-edge sequence number (order within row irrelevant: sum).
__global__ void k_count(const int* __restrict__ dst, int* __restrict__ counts,
                        int* __restrict__ seq, int E) {
    int t = blockIdx.x * blockDim.x + threadIdx.x;
    if (t < E) seq[t] = atomicAdd(&counts[dst[t]], 1);
}

// Block-local exclusive scan of counts + dinv/s1 computation.
__global__ void k_scan1(const int* __restrict__ counts, const float* __restrict__ x,
                        float* __restrict__ dinv, float* __restrict__ s1,
                        int* __restrict__ rowloc, int* __restrict__ blocksums) {
    __shared__ int s[256];
    int i = blockIdx.x * 256 + threadIdx.x;
    int c = counts[i];
    float d = rsqrtf((float)c + 1.0f);
    dinv[i] = d;
    s1[i] = x[i] * d;
    s[threadIdx.x] = c;
    __syncthreads();
    for (int off = 1; off < 256; off <<= 1) {
        int v = (threadIdx.x >= off) ? s[threadIdx.x - off] : 0;
        __syncthreads();
        s[threadIdx.x] += v;
        __syncthreads();
    }
    rowloc[i] = s[threadIdx.x] - c;  // block-local exclusive prefix
    if (threadIdx.x == 255) blocksums[blockIdx.x] = s[255];
}

// Atomic-free esrc fill via seq + finalized rowstart emission (blocks 0..255).
// Each block re-scans the 256 block sums in LDS instead of a separate scan kernel.
// NO fp32 atomics here (round-6 lesson: the t-atomicAdd fusion cost ~15us).
__global__ void k_fill(const int* __restrict__ src, const int* __restrict__ dst,
                       const int* __restrict__ rowloc, const int* __restrict__ seq,
                       const int* __restrict__ blocksums,
                       int* __restrict__ esrc, int* __restrict__ rowstart, int E) {
    __shared__ int boff[256];
    {
        int c = blocksums[threadIdx.x];
        boff[threadIdx.x] = c;
        __syncthreads();
        for (int off = 1; off < 256; off <<= 1) {
            int v = (threadIdx.x >= off) ? boff[threadIdx.x - off] : 0;
            __syncthreads();
            boff[threadIdx.x] += v;
            __syncthreads();
        }
        boff[threadIdx.x] -= c;      // exclusive
        __syncthreads();
    }
    int e = blockIdx.x * blockDim.x + threadIdx.x;
    if (e < E) {
        int d = dst[e];
        esrc[rowloc[d] + boff[d >> 8] + seq[e]] = src[e];
    }
    if (blockIdx.x < 256) {          // finalize rowstart (separate array: no race)
        int i = blockIdx.x * 256 + threadIdx.x;
        rowstart[i] = rowloc[i] + boff[blockIdx.x];
    }
}

// ---------------- Fused layer1-aggregation + layer1-activation + layer2 GEMM ----------------
// Prologue (threads 0..127): a[i] = dinv[i]*(s1[i] + sum s1[esrc]) for the block's 128 rows.
// Main: h1[i][k] = relu(a[i]*W1[k] + b1[k]); xws2[i][:] = (h1[i] @ W2) * dinv[i]  (fp16 out)
#define L12_R 8
__global__ void k_l1l2(const float* __restrict__ s1, const float* __restrict__ dinv,
                       const int* __restrict__ rowstart, const int* __restrict__ counts,
                       const int* __restrict__ esrc,
                       const float* __restrict__ W1, const float* __restrict__ b1,
                       const float* __restrict__ W2, __half* __restrict__ xws2, int N) {
    __shared__ float wb[128 * 2];
    __shared__ float W2s[128 * 64];
    __shared__ float als[128];       // a = dinv*t per row
    __shared__ float dls[128];       // dinv per row
    for (int idx = threadIdx.x; idx < 128; idx += 256) {
        wb[idx * 2] = W1[idx];
        wb[idx * 2 + 1] = b1[idx];
    }
    for (int idx = threadIdx.x; idx < 128 * 64 / 4; idx += 256)
        reinterpret_cast<float4*>(W2s)[idx] = reinterpret_cast<const float4*>(W2)[idx];
    if (threadIdx.x < 128) {
        int i = blockIdx.x * 128 + threadIdx.x;
        float a = 0.f, di = 0.f;
        if (i < N) {
            di = dinv[i];
            float t = s1[i];
            int s0 = rowstart[i], cn = counts[i];
            for (int p = s0; p < s0 + cn; ++p) t += s1[esrc[p]];
            a = di * t;
        }
        als[threadIdx.x] = a;
        dls[threadIdx.x] = di;
    }
    __syncthreads();

    int c4 = threadIdx.x & 15;
    int rg = threadIdx.x >> 4;
    int base = blockIdx.x * 128 + rg * L12_R;

    float a[L12_R];
#pragma unroll
    for (int r = 0; r < L12_R; ++r) a[r] = als[rg * L12_R + r];

    float4 acc[L12_R] = {};
    for (int k = 0; k < 128; ++k) {
        float2 w1b1 = *reinterpret_cast<const float2*>(&wb[k * 2]);
        float4 w2 = *reinterpret_cast<const float4*>(&W2s[k * 64 + c4 * 4]);
#pragma unroll
        for (int r = 0; r < L12_R; ++r) {
            float h = fmaxf(fmaf(a[r], w1b1.x, w1b1.y), 0.f);
            acc[r].x = fmaf(h, w2.x, acc[r].x);
            acc[r].y = fmaf(h, w2.y, acc[r].y);
            acc[r].z = fmaf(h, w2.z, acc[r].z);
            acc[r].w = fmaf(h, w2.w, acc[r].w);
        }
    }
#pragma unroll
    for (int r = 0; r < L12_R; ++r) {
        int i = base + r;
        if (i < N) {
            float di = dls[rg * L12_R + r];
            H4 o;
            o.h[0] = __floats2half2_rn(acc[r].x * di, acc[r].y * di);
            o.h[1] = __floats2half2_rn(acc[r].z * di, acc[r].w * di);
            reinterpret_cast<uint2*>(xws2)[(size_t)i * 16 + c4] = o.u;
        }
    }
}

// ---------------- Fused gather2 (+relu+bias) + layer3 GEMM (fp16 in/out) ----------------
__global__ void k_l2l3(const int* __restrict__ rowstart, const int* __restrict__ counts,
                       const int* __restrict__ esrc, const __half* __restrict__ xws2,
                       const float* __restrict__ dinv, const float* __restrict__ b2,
                       const float* __restrict__ W3, __half* __restrict__ xws3, int N) {
    __shared__ float W3s[64 * 32];
    __shared__ float h2s[16][64];
    __shared__ float b2s[64];
    for (int idx = threadIdx.x; idx < 64 * 32 / 4; idx += 256)
        reinterpret_cast<float4*>(W3s)[idx] = reinterpret_cast<const float4*>(W3)[idx];
    if (threadIdx.x < 64) b2s[threadIdx.x] = b2[threadIdx.x];
    __syncthreads();

    {
        int c4 = threadIdx.x & 15;
        int r  = threadIdx.x >> 4;
        int i  = blockIdx.x * 16 + r;
        if (i < N) {
            const uint2* x2 = reinterpret_cast<const uint2*>(xws2);
            H4 p; p.u = x2[(size_t)i * 16 + c4];
            float2 f0 = __half22float2(p.h[0]), f1 = __half22float2(p.h[1]);
            float4 acc = {f0.x, f0.y, f1.x, f1.y};
            int s0 = rowstart[i], cnt = counts[i];
            for (int q = s0; q < s0 + cnt; ++q) {
                int s = esrc[q];
                p.u = x2[(size_t)s * 16 + c4];
                f0 = __half22float2(p.h[0]); f1 = __half22float2(p.h[1]);
                acc.x += f0.x; acc.y += f0.y; acc.z += f1.x; acc.w += f1.y;
            }
            float di = dinv[i];
            float4 bv = *reinterpret_cast<const float4*>(&b2s[c4 * 4]);
            float4 h;
            h.x = fmaxf(fmaf(di, acc.x, bv.x), 0.f);
            h.y = fmaxf(fmaf(di, acc.y, bv.y), 0.f);
            h.z = fmaxf(fmaf(di, acc.z, bv.z), 0.f);
            h.w = fmaxf(fmaf(di, acc.w, bv.w), 0.f);
            *reinterpret_cast<float4*>(&h2s[r][c4 * 4]) = h;
        }
    }
    __syncthreads();
    {
        int c  = threadIdx.x & 15;
        int r2 = threadIdx.x >> 4;
        int i2 = blockIdx.x * 16 + r2;
        if (i2 >= N) return;
        float acc0 = 0.f, acc1 = 0.f;
#pragma unroll
        for (int k = 0; k < 64; ++k) {
            float h = h2s[r2][k];
            float2 w = *reinterpret_cast<const float2*>(&W3s[k * 32 + 2 * c]);
            acc0 = fmaf(h, w.x, acc0);
            acc1 = fmaf(h, w.y, acc1);
        }
        float di = dinv[i2];
        reinterpret_cast<__half2*>(xws3)[(size_t)i2 * 16 + c] =
            __floats2half2_rn(acc0 * di, acc1 * di);
    }
}

// ---------------- Fused gather3 (+relu+bias) + mean-pool partials (fp16 in) ----------------
// NO device-scope fence here (round-5 lesson: per-block __threadfence ~120us on gfx950).
__global__ void k_l3pool(const int* __restrict__ rowstart, const int* __restrict__ counts,
                         const int* __restrict__ esrc, const __half* __restrict__ xws3,
                         const float* __restrict__ dinv, const float* __restrict__ b3,
                         const int* __restrict__ batch, float* __restrict__ sums,
                         float* __restrict__ cnt, int N) {
    __shared__ float sl[64 * 32];
    __shared__ float cl[64];
    for (int idx = threadIdx.x; idx < 64 * 32; idx += 256) sl[idx] = 0.f;
    if (threadIdx.x < 64) cl[threadIdx.x] = 0.f;
    __syncthreads();

    int c4 = threadIdx.x & 7;
    int r  = threadIdx.x >> 3;
    int i  = blockIdx.x * 32 + r;
    if (i < N) {
        const uint2* x2 = reinterpret_cast<const uint2*>(xws3);
        H4 p; p.u = x2[(size_t)i * 8 + c4];
        float2 f0 = __half22float2(p.h[0]), f1 = __half22float2(p.h[1]);
        float4 acc = {f0.x, f0.y, f1.x, f1.y};
        int s0 = rowstart[i], cc = counts[i];
        for (int q = s0; q < s0 + cc; ++q) {
            int s = esrc[q];
            p.u = x2[(size_t)s * 8 + c4];
            f0 = __half22float2(p.h[0]); f1 = __half22float2(p.h[1]);
            acc.x += f0.x; acc.y += f0.y; acc.z += f1.x; acc.w += f1.y;
        }
        float di = dinv[i];
        const float4 bv = reinterpret_cast<const float4*>(b3)[c4];
        int g = batch[i];
        atomicAdd(&sl[g * 32 + c4 * 4 + 0], fmaxf(fmaf(di, acc.x, bv.x), 0.f));
        atomicAdd(&sl[g * 32 + c4 * 4 + 1], fmaxf(fmaf(di, acc.y, bv.y), 0.f));
        atomicAdd(&sl[g * 32 + c4 * 4 + 2], fmaxf(fmaf(di, acc.z, bv.z), 0.f));
        atomicAdd(&sl[g * 32 + c4 * 4 + 3], fmaxf(fmaf(di, acc.w, bv.w), 0.f));
        if (c4 == 0) atomicAdd(&cl[g], 1.f);
    }
    __syncthreads();

    int start = blockIdx.x * 32;
    if (start >= N) return;
    int g0 = batch[start];
    int g1 = batch[min(start + 31, N - 1)];
    int ng = g1 - g0 + 1;
    for (int idx = threadIdx.x; idx < ng * 32; idx += 256) {
        float v = sl[(g0 + idx / 32) * 32 + (idx & 31)];
        if (v != 0.f) atomicAdd(&sums[(g0 + idx / 32) * 32 + (idx & 31)], v);
    }
    for (int idx = threadIdx.x; idx < ng; idx += 256) {
        float v = cl[g0 + idx];
        if (v != 0.f) atomicAdd(&cnt[g0 + idx], v);
    }
}

__global__ void k_fc(const float* __restrict__ sums, const float* __restrict__ cnt,
                     const float* __restrict__ Wfc, const float* __restrict__ bfc,
                     float* __restrict__ out) {
    int t = blockIdx.x * blockDim.x + threadIdx.x;
    if (t >= 64 * 10) return;
    int g = t / 10, o = t % 10;
    float inv = 1.0f / fmaxf(cnt[g], 1.0f);
    float acc = bfc[o];
#pragma unroll
    for (int f = 0; f < 32; ++f) acc = fmaf(sums[g * 32 + f] * inv, Wfc[f * 10 + o], acc);
    out[t] = acc;
}

extern "C" void kernel_launch(void* const* d_in, const int* in_sizes, int n_in,
                              void* d_out, int out_size, void* d_ws, size_t ws_size,
                              hipStream_t stream) {
    const float* x    = (const float*)d_in[0];
    const int*   ei   = (const int*)d_in[1];
    const int*   batch= (const int*)d_in[2];
    const float* W1   = (const float*)d_in[3];
    const float* b1   = (const float*)d_in[4];
    const float* W2   = (const float*)d_in[5];
    const float* b2   = (const float*)d_in[6];
    const float* W3   = (const float*)d_in[7];
    const float* b3   = (const float*)d_in[8];
    const float* Wfc  = (const float*)d_in[9];
    const float* bfc  = (const float*)d_in[10];
    float* out = (float*)d_out;

    const int N = in_sizes[0];
    const int E = in_sizes[1] / 2;
    const int* src  = ei;
    const int* dstp = ei + E;

    char* ws = (char*)d_ws;
    size_t off = 0;
    auto alloc = [&](size_t bytes) { void* p = ws + off; off = (off + bytes + 15) & ~(size_t)15; return p; };
    // --- contiguous zero region: counts | sums | cnt ---
    int*    counts   = (int*)   alloc((size_t)N * 4);
    float*  sums     = (float*) alloc(64 * 32 * 4);
    float*  cnt      = (float*) alloc(64 * 4);
    size_t  zbytes   = (size_t)((char*)(cnt + 64) - (char*)counts);
    // --- rest ---
    int*    rowloc   = (int*)   alloc((size_t)N * 4);
    int*    rowstart = (int*)   alloc((size_t)N * 4);
    int*    seq      = (int*)   alloc((size_t)E * 4);
    int*    blocksums= (int*)   alloc(256 * 4);
    int*    esrc     = (int*)   alloc((size_t)E * 4);
    float*  dinv     = (float*) alloc((size_t)N * 4);
    float*  s1       = (float*) alloc((size_t)N * 4);
    __half* xws2     = (__half*)alloc((size_t)N * 64 * 2);
    __half* xws3     = (__half*)alloc((size_t)N * 32 * 2);

    auto blocks = [](long n) { return (int)((n + THREADS - 1) / THREADS); };

    hipMemsetAsync(counts, 0, zbytes, stream);

    k_count<<<blocks(E), THREADS, 0, stream>>>(dstp, counts, seq, E);
    k_scan1<<<N / 256, 256, 0, stream>>>(counts, x, dinv, s1, rowloc, blocksums);
    k_fill <<<blocks(E), THREADS, 0, stream>>>(src, dstp, rowloc, seq, blocksums,
                                               esrc, rowstart, E);
    k_l1l2<<<(N + 127) / 128, THREADS, 0, stream>>>(s1, dinv, rowstart, counts, esrc,
                                                    W1, b1, W2, xws2, N);
    k_l2l3<<<(N + 15) / 16, THREADS, 0, stream>>>(rowstart, counts, esrc, xws2, dinv, b2, W3, xws3, N);
    k_l3pool<<<(N + 31) / 32, THREADS, 0, stream>>>(rowstart, counts, esrc, xws3, dinv, b3, batch,
                                                    sums, cnt, N);
    k_fc<<<blocks(640), THREADS, 0, stream>>>(sums, cnt, Wfc, bfc, out);
}

// Round 8
// 177.463 us; speedup vs baseline: 1.8498x; 1.1289x over previous
//
#include <hip/hip_runtime.h>
#include <hip/hip_fp16.h>

#define THREADS 256

typedef union { uint2 u; __half2 h[2]; } H4;
typedef union { uint4 u; __half2 h[4]; } H8;

// ---------------- CSR build ----------------

// counts[d]++ and record per-edge sequence number (order within row irrelevant: sum).
__global__ void k_count(const int* __restrict__ dst, int* __restrict__ counts,
                        int* __restrict__ seq, int E) {
    int t = blockIdx.x * blockDim.x + threadIdx.x;
    if (t < E) seq[t] = atomicAdd(&counts[dst[t]], 1);
}

// Block-local exclusive scan of counts + dinv/s1 computation.
__global__ void k_scan1(const int* __restrict__ counts, const float* __restrict__ x,
                        float* __restrict__ dinv, float* __restrict__ s1,
                        int* __restrict__ rowloc, int* __restrict__ blocksums) {
    __shared__ int s[256];
    int i = blockIdx.x * 256 + threadIdx.x;
    int c = counts[i];
    float d = rsqrtf((float)c + 1.0f);
    dinv[i] = d;
    s1[i] = x[i] * d;
    s[threadIdx.x] = c;
    __syncthreads();
    for (int off = 1; off < 256; off <<= 1) {
        int v = (threadIdx.x >= off) ? s[threadIdx.x - off] : 0;
        __syncthreads();
        s[threadIdx.x] += v;
        __syncthreads();
    }
    rowloc[i] = s[threadIdx.x] - c;  // block-local exclusive prefix
    if (threadIdx.x == 255) blocksums[blockIdx.x] = s[255];
}

// Atomic-free esrc fill via seq + finalized rowstart emission (blocks 0..255).
// NO fp32 atomics (round-6 lesson), NO device fences (round-5 lesson).
__global__ void k_fill(const int* __restrict__ src, const int* __restrict__ dst,
                       const int* __restrict__ rowloc, const int* __restrict__ seq,
                       const int* __restrict__ blocksums,
                       int* __restrict__ esrc, int* __restrict__ rowstart, int E) {
    __shared__ int boff[256];
    {
        int c = blocksums[threadIdx.x];
        boff[threadIdx.x] = c;
        __syncthreads();
        for (int off = 1; off < 256; off <<= 1) {
            int v = (threadIdx.x >= off) ? boff[threadIdx.x - off] : 0;
            __syncthreads();
            boff[threadIdx.x] += v;
            __syncthreads();
        }
        boff[threadIdx.x] -= c;      // exclusive
        __syncthreads();
    }
    int e = blockIdx.x * blockDim.x + threadIdx.x;
    if (e < E) {
        int d = dst[e];
        esrc[rowloc[d] + boff[d >> 8] + seq[e]] = src[e];
    }
    if (blockIdx.x < 256) {
        int i = blockIdx.x * 256 + threadIdx.x;
        rowstart[i] = rowloc[i] + boff[blockIdx.x];
    }
}

// ---------------- Fused layer1-aggregation + activation + layer2 GEMM ----------------
#define L12_R 8
__global__ void k_l1l2(const float* __restrict__ s1, const float* __restrict__ dinv,
                       const int* __restrict__ rowstart, const int* __restrict__ counts,
                       const int* __restrict__ esrc,
                       const float* __restrict__ W1, const float* __restrict__ b1,
                       const float* __restrict__ W2, __half* __restrict__ xws2, int N) {
    __shared__ float wb[128 * 2];
    __shared__ float W2s[128 * 64];
    __shared__ float als[128];
    __shared__ float dls[128];
    for (int idx = threadIdx.x; idx < 128; idx += 256) {
        wb[idx * 2] = W1[idx];
        wb[idx * 2 + 1] = b1[idx];
    }
    for (int idx = threadIdx.x; idx < 128 * 64 / 4; idx += 256)
        reinterpret_cast<float4*>(W2s)[idx] = reinterpret_cast<const float4*>(W2)[idx];
    if (threadIdx.x < 128) {
        int i = blockIdx.x * 128 + threadIdx.x;
        float a = 0.f, di = 0.f;
        if (i < N) {
            di = dinv[i];
            float t = s1[i];
            int p = rowstart[i], end = p + counts[i];
            for (; p + 3 < end; p += 4) {       // 4-way MLP unroll
                int a0 = esrc[p], a1 = esrc[p + 1], a2 = esrc[p + 2], a3 = esrc[p + 3];
                float v0 = s1[a0], v1 = s1[a1], v2 = s1[a2], v3 = s1[a3];
                t += (v0 + v1) + (v2 + v3);
            }
            for (; p < end; ++p) t += s1[esrc[p]];
            a = di * t;
        }
        als[threadIdx.x] = a;
        dls[threadIdx.x] = di;
    }
    __syncthreads();

    int c4 = threadIdx.x & 15;
    int rg = threadIdx.x >> 4;
    int base = blockIdx.x * 128 + rg * L12_R;

    float a[L12_R];
#pragma unroll
    for (int r = 0; r < L12_R; ++r) a[r] = als[rg * L12_R + r];

    float4 acc[L12_R] = {};
    for (int k = 0; k < 128; ++k) {
        float2 w1b1 = *reinterpret_cast<const float2*>(&wb[k * 2]);
        float4 w2 = *reinterpret_cast<const float4*>(&W2s[k * 64 + c4 * 4]);
#pragma unroll
        for (int r = 0; r < L12_R; ++r) {
            float h = fmaxf(fmaf(a[r], w1b1.x, w1b1.y), 0.f);
            acc[r].x = fmaf(h, w2.x, acc[r].x);
            acc[r].y = fmaf(h, w2.y, acc[r].y);
            acc[r].z = fmaf(h, w2.z, acc[r].z);
            acc[r].w = fmaf(h, w2.w, acc[r].w);
        }
    }
#pragma unroll
    for (int r = 0; r < L12_R; ++r) {
        int i = base + r;
        if (i < N) {
            float di = dls[rg * L12_R + r];
            H4 o;
            o.h[0] = __floats2half2_rn(acc[r].x * di, acc[r].y * di);
            o.h[1] = __floats2half2_rn(acc[r].z * di, acc[r].w * di);
            reinterpret_cast<uint2*>(xws2)[(size_t)i * 16 + c4] = o.u;
        }
    }
}

// ---------------- Fused gather2 (+relu+bias) + layer3 GEMM (fp16 in/out) ----------------
// 32 rows/block, 8 threads/row, uint4 (8 fp16) gathers, 4-way MLP unroll.
__global__ void k_l2l3(const int* __restrict__ rowstart, const int* __restrict__ counts,
                       const int* __restrict__ esrc, const __half* __restrict__ xws2,
                       const float* __restrict__ dinv, const float* __restrict__ b2,
                       const float* __restrict__ W3, __half* __restrict__ xws3, int N) {
    __shared__ float W3s[64 * 32];   // 8 KB
    __shared__ float h2s[32][68];    // padded stride 68 -> phase-B reads conflict-free
    __shared__ float b2s[64];
    for (int idx = threadIdx.x; idx < 64 * 32 / 4; idx += 256)
        reinterpret_cast<float4*>(W3s)[idx] = reinterpret_cast<const float4*>(W3)[idx];
    if (threadIdx.x < 64) b2s[threadIdx.x] = b2[threadIdx.x];
    __syncthreads();

    {
        int c8 = threadIdx.x & 7;        // 8-feature group
        int r  = threadIdx.x >> 3;       // 0..31
        int i  = blockIdx.x * 32 + r;
        if (i < N) {
            const uint4* x4 = reinterpret_cast<const uint4*>(xws2);   // row = 8 uint4
            H8 p; p.u = x4[(size_t)i * 8 + c8];
            float acc[8];
#pragma unroll
            for (int j = 0; j < 4; ++j) {
                float2 f = __half22float2(p.h[j]);
                acc[2 * j] = f.x; acc[2 * j + 1] = f.y;
            }
            int q = rowstart[i], end = q + counts[i];
            for (; q + 3 < end; q += 4) {    // 4 independent gathers in flight
                int sa = esrc[q], sb = esrc[q + 1], sc = esrc[q + 2], sd = esrc[q + 3];
                H8 pa, pb, pc, pd;
                pa.u = x4[(size_t)sa * 8 + c8];
                pb.u = x4[(size_t)sb * 8 + c8];
                pc.u = x4[(size_t)sc * 8 + c8];
                pd.u = x4[(size_t)sd * 8 + c8];
#pragma unroll
                for (int j = 0; j < 4; ++j) {
                    float2 fa = __half22float2(pa.h[j]);
                    float2 fb = __half22float2(pb.h[j]);
                    float2 fc = __half22float2(pc.h[j]);
                    float2 fd = __half22float2(pd.h[j]);
                    acc[2 * j]     += (fa.x + fb.x) + (fc.x + fd.x);
                    acc[2 * j + 1] += (fa.y + fb.y) + (fc.y + fd.y);
                }
            }
            for (; q < end; ++q) {
                H8 pe; pe.u = x4[(size_t)esrc[q] * 8 + c8];
#pragma unroll
                for (int j = 0; j < 4; ++j) {
                    float2 f = __half22float2(pe.h[j]);
                    acc[2 * j] += f.x; acc[2 * j + 1] += f.y;
                }
            }
            float di = dinv[i];
            float4 hv0, hv1;
            float* hv = &hv0.x;
#pragma unroll
            for (int j = 0; j < 8; ++j)
                (j < 4 ? (&hv0.x)[j] : (&hv1.x)[j - 4]) =
                    fmaxf(fmaf(di, acc[j], b2s[c8 * 8 + j]), 0.f);
            (void)hv;
            *reinterpret_cast<float4*>(&h2s[r][c8 * 8])     = hv0;
            *reinterpret_cast<float4*>(&h2s[r][c8 * 8 + 4]) = hv1;
        }
    }
    __syncthreads();
    {
        int c  = threadIdx.x & 7;        // 4-col group
        int r2 = threadIdx.x >> 3;       // 0..31
        int i2 = blockIdx.x * 32 + r2;
        if (i2 >= N) return;
        float4 acc = {};
#pragma unroll
        for (int k = 0; k < 64; ++k) {
            float h = h2s[r2][k];
            float4 w = *reinterpret_cast<const float4*>(&W3s[k * 32 + c * 4]);
            acc.x = fmaf(h, w.x, acc.x);
            acc.y = fmaf(h, w.y, acc.y);
            acc.z = fmaf(h, w.z, acc.z);
            acc.w = fmaf(h, w.w, acc.w);
        }
        float di = dinv[i2];
        H4 o;
        o.h[0] = __floats2half2_rn(acc.x * di, acc.y * di);
        o.h[1] = __floats2half2_rn(acc.z * di, acc.w * di);
        reinterpret_cast<uint2*>(xws3)[(size_t)i2 * 8 + c] = o.u;
    }
}

// ---------------- Fused gather3 (+relu+bias) + mean-pool partials (fp16 in) ----------------
// 64 rows/block, 4 threads/row, uint4 gathers, 4-way MLP unroll. No device fences.
__global__ void k_l3pool(const int* __restrict__ rowstart, const int* __restrict__ counts,
                         const int* __restrict__ esrc, const __half* __restrict__ xws3,
                         const float* __restrict__ dinv, const float* __restrict__ b3,
                         const int* __restrict__ batch, float* __restrict__ sums,
                         float* __restrict__ cnt, int N) {
    __shared__ float sl[64 * 32];
    __shared__ float cl[64];
    for (int idx = threadIdx.x; idx < 64 * 32; idx += 256) sl[idx] = 0.f;
    if (threadIdx.x < 64) cl[threadIdx.x] = 0.f;
    __syncthreads();

    int c = threadIdx.x & 3;         // 8-feature group
    int r = threadIdx.x >> 2;        // 0..63
    int i = blockIdx.x * 64 + r;
    if (i < N) {
        const uint4* x4 = reinterpret_cast<const uint4*>(xws3);   // row = 4 uint4
        H8 p; p.u = x4[(size_t)i * 4 + c];
        float acc[8];
#pragma unroll
        for (int j = 0; j < 4; ++j) {
            float2 f = __half22float2(p.h[j]);
            acc[2 * j] = f.x; acc[2 * j + 1] = f.y;
        }
        int q = rowstart[i], end = q + counts[i];
        for (; q + 3 < end; q += 4) {
            int sa = esrc[q], sb = esrc[q + 1], sc = esrc[q + 2], sd = esrc[q + 3];
            H8 pa, pb, pc, pd;
            pa.u = x4[(size_t)sa * 4 + c];
            pb.u = x4[(size_t)sb * 4 + c];
            pc.u = x4[(size_t)sc * 4 + c];
            pd.u = x4[(size_t)sd * 4 + c];
#pragma unroll
            for (int j = 0; j < 4; ++j) {
                float2 fa = __half22float2(pa.h[j]);
                float2 fb = __half22float2(pb.h[j]);
                float2 fc = __half22float2(pc.h[j]);
                float2 fd = __half22float2(pd.h[j]);
                acc[2 * j]     += (fa.x + fb.x) + (fc.x + fd.x);
                acc[2 * j + 1] += (fa.y + fb.y) + (fc.y + fd.y);
            }
        }
        for (; q < end; ++q) {
            H8 pe; pe.u = x4[(size_t)esrc[q] * 4 + c];
#pragma unroll
            for (int j = 0; j < 4; ++j) {
                float2 f = __half22float2(pe.h[j]);
                acc[2 * j] += f.x; acc[2 * j + 1] += f.y;
            }
        }
        float di = dinv[i];
        int g = batch[i];
#pragma unroll
        for (int j = 0; j < 8; ++j)
            atomicAdd(&sl[g * 32 + c * 8 + j], fmaxf(fmaf(di, acc[j], b3[c * 8 + j]), 0.f));
        if (c == 0) atomicAdd(&cl[g], 1.f);
    }
    __syncthreads();

    int start = blockIdx.x * 64;
    if (start >= N) return;
    int g0 = batch[start];
    int g1 = batch[min(start + 63, N - 1)];
    int ng = g1 - g0 + 1;
    for (int idx = threadIdx.x; idx < ng * 32; idx += 256) {
        float v = sl[(g0 + idx / 32) * 32 + (idx & 31)];
        if (v != 0.f) atomicAdd(&sums[(g0 + idx / 32) * 32 + (idx & 31)], v);
    }
    for (int idx = threadIdx.x; idx < ng; idx += 256) {
        float v = cl[g0 + idx];
        if (v != 0.f) atomicAdd(&cnt[g0 + idx], v);
    }
}

__global__ void k_fc(const float* __restrict__ sums, const float* __restrict__ cnt,
                     const float* __restrict__ Wfc, const float* __restrict__ bfc,
                     float* __restrict__ out) {
    int t = blockIdx.x * blockDim.x + threadIdx.x;
    if (t >= 64 * 10) return;
    int g = t / 10, o = t % 10;
    float inv = 1.0f / fmaxf(cnt[g], 1.0f);
    float acc = bfc[o];
#pragma unroll
    for (int f = 0; f < 32; ++f) acc = fmaf(sums[g * 32 + f] * inv, Wfc[f * 10 + o], acc);
    out[t] = acc;
}

extern "C" void kernel_launch(void* const* d_in, const int* in_sizes, int n_in,
                              void* d_out, int out_size, void* d_ws, size_t ws_size,
                              hipStream_t stream) {
    const float* x    = (const float*)d_in[0];
    const int*   ei   = (const int*)d_in[1];
    const int*   batch= (const int*)d_in[2];
    const float* W1   = (const float*)d_in[3];
    const float* b1   = (const float*)d_in[4];
    const float* W2   = (const float*)d_in[5];
    const float* b2   = (const float*)d_in[6];
    const float* W3   = (const float*)d_in[7];
    const float* b3   = (const float*)d_in[8];
    const float* Wfc  = (const float*)d_in[9];
    const float* bfc  = (const float*)d_in[10];
    float* out = (float*)d_out;

    const int N = in_sizes[0];
    const int E = in_sizes[1] / 2;
    const int* src  = ei;
    const int* dstp = ei + E;

    char* ws = (char*)d_ws;
    size_t off = 0;
    auto alloc = [&](size_t bytes) { void* p = ws + off; off = (off + bytes + 15) & ~(size_t)15; return p; };
    // --- contiguous zero region: counts | sums | cnt ---
    int*    counts   = (int*)   alloc((size_t)N * 4);
    float*  sums     = (float*) alloc(64 * 32 * 4);
    float*  cnt      = (float*) alloc(64 * 4);
    size_t  zbytes   = (size_t)((char*)(cnt + 64) - (char*)counts);
    // --- rest ---
    int*    rowloc   = (int*)   alloc((size_t)N * 4);
    int*    rowstart = (int*)   alloc((size_t)N * 4);
    int*    seq      = (int*)   alloc((size_t)E * 4);
    int*    blocksums= (int*)   alloc(256 * 4);
    int*    esrc     = (int*)   alloc((size_t)E * 4);
    float*  dinv     = (float*) alloc((size_t)N * 4);
    float*  s1       = (float*) alloc((size_t)N * 4);
    __half* xws2     = (__half*)alloc((size_t)N * 64 * 2);
    __half* xws3     = (__half*)alloc((size_t)N * 32 * 2);

    auto blocks = [](long n) { return (int)((n + THREADS - 1) / THREADS); };

    hipMemsetAsync(counts, 0, zbytes, stream);

    k_count<<<blocks(E), THREADS, 0, stream>>>(dstp, counts, seq, E);
    k_scan1<<<N / 256, 256, 0, stream>>>(counts, x, dinv, s1, rowloc, blocksums);
    k_fill <<<blocks(E), THREADS, 0, stream>>>(src, dstp, rowloc, seq, blocksums,
                                               esrc, rowstart, E);
    k_l1l2<<<(N + 127) / 128, THREADS, 0, stream>>>(s1, dinv, rowstart, counts, esrc,
                                                    W1, b1, W2, xws2, N);
    k_l2l3<<<(N + 31) / 32, THREADS, 0, stream>>>(rowstart, counts, esrc, xws2, dinv, b2, W3, xws3, N);
    k_l3pool<<<(N + 63) / 64, THREADS, 0, stream>>>(rowstart, counts, esrc, xws3, dinv, b3, batch,
                                                    sums, cnt, N);
    k_fc<<<blocks(640), THREADS, 0, stream>>>(sums, cnt, Wfc, bfc, out);
}